// Round 17
// baseline (382.782 us; speedup 1.0000x reference)
//
#include <hip/hip_runtime.h>

typedef __bf16 bf16x8 __attribute__((ext_vector_type(8)));
typedef __bf16 bf16x4 __attribute__((ext_vector_type(4)));
typedef float  f32x4  __attribute__((ext_vector_type(4)));

#define GAMMA 0.99f

__device__ __forceinline__ void gload_lds16(const void* g, void* l) {
  __builtin_amdgcn_global_load_lds(
      (const __attribute__((address_space(1))) void*)g,
      (__attribute__((address_space(3))) void*)l, 16, 0, 0);
}

#define VMCNT(n) asm volatile("s_waitcnt vmcnt(" #n ")" ::: "memory")
#define BAR() __builtin_amdgcn_s_barrier()
#define MFMA(d, a, b) d = __builtin_amdgcn_mfma_f32_16x16x32_bf16(a, b, d, 0, 0, 0)

// --------------------------------------------------- prep: scan + W cvt ----
// block 0       : discounted-return scan (1024 threads)
// blocks 1..512 : W1/W2 transpose+cvt -> BT1/BT2 (4 subtiles of 32x32 each)
__global__ __launch_bounds__(1024) void prep(
    const float* __restrict__ rw, float* __restrict__ G,
    const float* __restrict__ W1, const float* __restrict__ W2,
    __bf16* __restrict__ BT1, __bf16* __restrict__ BT2) {
  __shared__ float smem[4224];
  const int blk = blockIdx.x;
  const int t = threadIdx.x;
  if (blk == 0) {
    float* sv = smem;
    const float4* rp = (const float4*)(rw + t * 64);
    float4 lv[16];
#pragma unroll
    for (int i = 0; i < 16; ++i) lv[i] = rp[i];
    float loc[64];
#pragma unroll
    for (int i = 0; i < 16; ++i) {
      loc[4 * i + 0] = lv[i].x; loc[4 * i + 1] = lv[i].y;
      loc[4 * i + 2] = lv[i].z; loc[4 * i + 3] = lv[i].w;
    }
    float g = 0.f;
#pragma unroll
    for (int j = 63; j >= 0; --j) { g = loc[j] + GAMMA * g; loc[j] = g; }
    sv[t] = g;
    float W = GAMMA;
#pragma unroll
    for (int i = 0; i < 6; ++i) W *= W;  // gamma^64
    float v = g;
    for (int s = 1; s < 1024; s <<= 1) {
      __syncthreads();
      float o = (t + s < 1024) ? sv[t + s] : 0.f;
      __syncthreads();
      v += W * o;
      sv[t] = v;
      W *= W;
    }
    __syncthreads();
    const float nxt = (t < 1023) ? sv[t + 1] : 0.f;
    float pw = GAMMA;
#pragma unroll
    for (int j = 63; j >= 0; --j) {
      G[t * 64 + j] = loc[j] + pw * nxt;
      pw *= GAMMA;
    }
  } else {
    const int sub = t >> 8, tt = t & 255;
    const int wi = (blk - 1) * 4 + sub;  // 0..2047
    const float* W = (wi >= 1024) ? W2 : W1;
    __bf16* O = (wi >= 1024) ? BT2 : BT1;
    const int tile = wi & 1023;
    const int ti = tile >> 5, tj = tile & 31;
    float* s = smem + sub * 1056;  // [32][33]
    const int rr = tt >> 3, c4 = (tt & 7) * 4;
    float4 v = *(const float4*)(W + (size_t)(ti * 32 + rr) * 1024 + tj * 32 + c4);
    s[rr * 33 + c4 + 0] = v.x; s[rr * 33 + c4 + 1] = v.y;
    s[rr * 33 + c4 + 2] = v.z; s[rr * 33 + c4 + 3] = v.w;
    __syncthreads();
    bf16x4 o = {(__bf16)s[(c4 + 0) * 33 + rr], (__bf16)s[(c4 + 1) * 33 + rr],
                (__bf16)s[(c4 + 2) * 33 + rr], (__bf16)s[(c4 + 3) * 33 + rr]};
    *(bf16x4*)(O + (size_t)(tj * 32 + rr) * 1024 + ti * 32 + c4) = o;
  }
}

// ----------------------------------------------------- conv (per chunk) ----
// obs fp32 -> bf16, one 16384-row chunk (16.7M elems): 512 blocks x 1024 thr.
// NT loads (stream), regular stores (L3 write-allocate keeps chunk resident
// for the immediately-following gemm1 chunk).
__global__ __launch_bounds__(1024) void conv(const float* __restrict__ obs,
                                             __bf16* __restrict__ obsb) {
  const size_t base = (size_t)blockIdx.x * 32768 + (size_t)threadIdx.x * 8;
#pragma unroll
  for (int it = 0; it < 4; ++it) {
    const size_t e = base + (size_t)it * 8192;
    const f32x4* p = (const f32x4*)(obs + e);
    f32x4 u0 = __builtin_nontemporal_load(p);
    f32x4 u1 = __builtin_nontemporal_load(p + 1);
    bf16x8 o = {(__bf16)u0[0], (__bf16)u0[1], (__bf16)u0[2], (__bf16)u0[3],
                (__bf16)u1[0], (__bf16)u1[1], (__bf16)u1[2], (__bf16)u1[3]};
    *(bf16x8*)(obsb + e) = o;
  }
}

// ---------------------------------------------------------------------------
// GEMM core (R11 form): BM=BN=256, BK=32, 512 thr = 8 waves (2x4). 4 LDS
// buffers of 32 KB {A 16K | B 16K}, bf16, 64-B rows, chunk c at slot
// c^((r>>1)&3). Depth-3 counted-vmcnt pipeline (VMCNT(12) steady, peel
// 8/4/0). SWAPPED MFMA -> direct vector stores. Per-chunk grid = 256 blocks
// (64 m-stripes x 4 nb), mb = mbase + XCD-grouped local index.
// launch_bounds (512,2): (512,4) caps VGPR at 64 -> acc spills (R5 lesson).
// ---------------------------------------------------------------------------
#define GEMM_PRELUDE(APTR, BPTR)                                               \
  extern __shared__ char lds[];                                                \
  const int t = threadIdx.x, lane = t & 63, w = t >> 6;                        \
  const int wsr = w >> 2, wsc = w & 3, g = lane >> 4, l15 = lane & 15;         \
  const int bid = blockIdx.x;                                                  \
  const int mb = mbase + (bid & 7) * 8 + (bid >> 5);                           \
  const int nb = (bid >> 3) & 3;                                               \
  const size_t stg_off =                                                       \
      (size_t)(t >> 2) * 2048 + (size_t)(((t & 3) ^ ((t >> 3) & 3)) * 16);     \
  const char* Ag = (const char*)(APTR) + (size_t)mb * 524288 + stg_off;        \
  const char* Bg = (const char*)(BPTR) + (size_t)nb * 524288 + stg_off;        \
  const int csw = (g ^ ((l15 >> 1) & 3)) << 4;                                 \
  const int arb = (wsr * 64 + l15) * 64 + csw;                                 \
  const int brb = (wsc * 32 + l15) * 64 + csw + 16384;                         \
  f32x4 acc[2][4][2][2];                                                       \
  const f32x4 zero = {0.f, 0.f, 0.f, 0.f};                                     \
  _Pragma("unroll") for (int a_ = 0; a_ < 2; ++a_)                             \
  _Pragma("unroll") for (int b_ = 0; b_ < 4; ++b_)                             \
  _Pragma("unroll") for (int c_ = 0; c_ < 2; ++c_)                             \
  _Pragma("unroll") for (int d_ = 0; d_ < 2; ++d_)                             \
    acc[a_][b_][c_][d_] = zero;                                                \
  auto STA = [&](int buf, int kt) {                                            \
    const char* s = Ag + kt * 64;                                              \
    char* d = lds + buf * 32768 + t * 16;                                      \
    gload_lds16(s, d);                                                         \
    gload_lds16(s + 262144, d + 8192);                                         \
  };                                                                           \
  auto STB = [&](int buf, int kt) {                                            \
    const char* s = Bg + kt * 64;                                              \
    char* d = lds + buf * 32768 + 16384 + t * 16;                              \
    gload_lds16(s, d);                                                         \
    gload_lds16(s + 262144, d + 8192);                                         \
  };                                                                           \
  auto COMPUTE = [&](int bc) {                                                 \
    const char* ab = lds + bc * 32768;                                         \
    bf16x8 bfr[2][2], afr[4];                                                  \
    _Pragma("unroll") for (int nh = 0; nh < 2; ++nh)                           \
    _Pragma("unroll") for (int j = 0; j < 2; ++j)                              \
      bfr[nh][j] = *(const bf16x8*)(ab + brb + (nh * 128 + j * 16) * 64);      \
    _Pragma("unroll") for (int i = 0; i < 4; ++i)                              \
      afr[i] = *(const bf16x8*)(ab + arb + (i * 16) * 64);                     \
    __builtin_amdgcn_s_setprio(1);                                             \
    _Pragma("unroll") for (int i = 0; i < 4; ++i)                              \
    _Pragma("unroll") for (int nh = 0; nh < 2; ++nh)                           \
    _Pragma("unroll") for (int j = 0; j < 2; ++j)                              \
      MFMA(acc[0][i][nh][j], bfr[nh][j], afr[i]);                              \
    __builtin_amdgcn_s_setprio(0);                                             \
    _Pragma("unroll") for (int i = 0; i < 4; ++i)                              \
      afr[i] = *(const bf16x8*)(ab + arb + ((128 + i * 16) * 64));             \
    __builtin_amdgcn_s_setprio(1);                                             \
    _Pragma("unroll") for (int i = 0; i < 4; ++i)                              \
    _Pragma("unroll") for (int nh = 0; nh < 2; ++nh)                           \
    _Pragma("unroll") for (int j = 0; j < 2; ++j)                              \
      MFMA(acc[1][i][nh][j], bfr[nh][j], afr[i]);                              \
    __builtin_amdgcn_s_setprio(0);                                             \
  };

#define KLOOP_D3()                                                             \
  STA(0, 0); STB(0, 0);                                                        \
  STA(1, 1); STB(1, 1);                                                        \
  STA(2, 2); STB(2, 2);                                                        \
  int bc = 0;                                                                  \
  for (int kt = 0; kt < 29; ++kt) {                                            \
    int bs = bc + 3; if (bs >= 4) bs -= 4;                                     \
    STA(bs, kt + 3);                                                           \
    STB(bs, kt + 3);                                                           \
    VMCNT(12);                                                                 \
    BAR();                                                                     \
    COMPUTE(bc);                                                               \
    BAR();                                                                     \
    bc = (bc + 1) & 3;                                                         \
  }                                                                            \
  VMCNT(8);  BAR(); COMPUTE(bc); BAR(); bc = (bc + 1) & 3;                     \
  VMCNT(4);  BAR(); COMPUTE(bc); BAR(); bc = (bc + 1) & 3;                     \
  VMCNT(0);  BAR(); COMPUTE(bc);

// ---------------------------------------------------------------- GEMM1 ----
// h1 = relu(obs_bf16 @ W1 + b1); direct bf16x4 stores
__global__ __launch_bounds__(512, 2) void gemm1(
    const __bf16* __restrict__ obsb, const __bf16* __restrict__ BT1,
    const float* __restrict__ b1, __bf16* __restrict__ h1, int mbase) {
  GEMM_PRELUDE(obsb, BT1)
  KLOOP_D3()
  f32x4 b1q[2][2];
#pragma unroll
  for (int nh = 0; nh < 2; ++nh)
#pragma unroll
    for (int j = 0; j < 2; ++j)
      b1q[nh][j] =
          *(const f32x4*)(b1 + nb * 256 + nh * 128 + wsc * 32 + j * 16 + g * 4);
#pragma unroll
  for (int mh = 0; mh < 2; ++mh)
#pragma unroll
    for (int i = 0; i < 4; ++i) {
      const size_t mrow = (size_t)(mb * 256 + mh * 128 + wsr * 64 + i * 16 + l15);
#pragma unroll
      for (int nh = 0; nh < 2; ++nh)
#pragma unroll
        for (int j = 0; j < 2; ++j) {
          f32x4 v = acc[mh][i][nh][j];
          v.x += b1q[nh][j].x; v.y += b1q[nh][j].y;
          v.z += b1q[nh][j].z; v.w += b1q[nh][j].w;
          v.x = v.x > 0.f ? v.x : 0.f;
          v.y = v.y > 0.f ? v.y : 0.f;
          v.z = v.z > 0.f ? v.z : 0.f;
          v.w = v.w > 0.f ? v.w : 0.f;
          bf16x4 o = {(__bf16)v.x, (__bf16)v.y, (__bf16)v.z, (__bf16)v.w};
          *(bf16x4*)(h1 + mrow * 1024 + nb * 256 + nh * 128 + wsc * 32 +
                     j * 16 + g * 4) = o;
        }
    }
}

// ---------------------------------------------------------------- GEMM2 ----
// h2 = relu(h1 @ W2 + b2); fused V4[nb][m] = sum_c h2[m][c]*W3[c]
__global__ __launch_bounds__(512, 2) void gemm2(
    const __bf16* __restrict__ h1, const __bf16* __restrict__ BT2,
    const float* __restrict__ b2, const float* __restrict__ W3,
    float* __restrict__ V4, int mbase) {
  GEMM_PRELUDE(h1, BT2)
  KLOOP_D3()
  f32x4 b2q[2][2], w3q[2][2];
#pragma unroll
  for (int nh = 0; nh < 2; ++nh)
#pragma unroll
    for (int j = 0; j < 2; ++j) {
      const int C = nb * 256 + nh * 128 + wsc * 32 + j * 16 + g * 4;
      b2q[nh][j] = *(const f32x4*)(b2 + C);
      w3q[nh][j] = *(const f32x4*)(W3 + C);
    }
  float p[2][4];
#pragma unroll
  for (int mh = 0; mh < 2; ++mh)
#pragma unroll
    for (int i = 0; i < 4; ++i) {
      float s = 0.f;
#pragma unroll
      for (int nh = 0; nh < 2; ++nh)
#pragma unroll
        for (int j = 0; j < 2; ++j) {
          f32x4 v = acc[mh][i][nh][j];
          v.x += b2q[nh][j].x; v.y += b2q[nh][j].y;
          v.z += b2q[nh][j].z; v.w += b2q[nh][j].w;
          v.x = v.x > 0.f ? v.x : 0.f;
          v.y = v.y > 0.f ? v.y : 0.f;
          v.z = v.z > 0.f ? v.z : 0.f;
          v.w = v.w > 0.f ? v.w : 0.f;
          s += v.x * w3q[nh][j].x + v.y * w3q[nh][j].y +
               v.z * w3q[nh][j].z + v.w * w3q[nh][j].w;
        }
      p[mh][i] = s;
    }
#pragma unroll
  for (int mh = 0; mh < 2; ++mh)
#pragma unroll
    for (int i = 0; i < 4; ++i) {
      p[mh][i] += __shfl_xor(p[mh][i], 16, 64);
      p[mh][i] += __shfl_xor(p[mh][i], 32, 64);
    }
  float* vp = (float*)lds;  // buf0; final COMPUTE reads buf3 -> no overlap
  if (g == 0) {
#pragma unroll
    for (int mh = 0; mh < 2; ++mh)
#pragma unroll
      for (int i = 0; i < 4; ++i)
        vp[wsc * 256 + mh * 128 + wsr * 64 + i * 16 + l15] = p[mh][i];
  }
  __syncthreads();
  if (t < 256) {
    float s = vp[t] + vp[256 + t] + vp[512 + t] + vp[768 + t];
    V4[(size_t)nb * 65536 + mb * 256 + t] = s;
  }
}

// ---------------------------------------------------------------- final ----
__global__ __launch_bounds__(256) void final_kernel(const float* __restrict__ G,
                                                    const float* __restrict__ V4,
                                                    const float* __restrict__ b3,
                                                    float* __restrict__ out) {
  int i = blockIdx.x * 256 + threadIdx.x;
  out[i] = G[i] - (V4[i] + V4[65536 + i] + V4[131072 + i] + V4[196608 + i] + b3[0]);
}

extern "C" void kernel_launch(void* const* d_in, const int* in_sizes, int n_in,
                              void* d_out, int out_size, void* d_ws, size_t ws_size,
                              hipStream_t stream) {
  const float* rewards = (const float*)d_in[0];
  const float* obs = (const float*)d_in[1];
  const float* W1 = (const float*)d_in[2];
  const float* b1 = (const float*)d_in[3];
  const float* W2 = (const float*)d_in[4];
  const float* b2 = (const float*)d_in[5];
  const float* W3 = (const float*)d_in[6];
  const float* b3 = (const float*)d_in[7];
  float* out = (float*)d_out;

  char* ws = (char*)d_ws;
  __bf16* BT1 = (__bf16*)(ws);                 // 2 MiB
  __bf16* BT2 = (__bf16*)(ws + (2u << 20));    // 2 MiB
  float* V4 = (float*)(ws + (4u << 20));       // 1 MiB
  float* G = (float*)(ws + (5u << 20));        // 256 KiB
  __bf16* obsb = (__bf16*)(ws + (8u << 20));   // 128 MiB
  __bf16* h1 = (__bf16*)(ws + (136u << 20));   // 128 MiB

  (void)hipFuncSetAttribute((const void*)gemm1,
                            hipFuncAttributeMaxDynamicSharedMemorySize, 131072);
  (void)hipFuncSetAttribute((const void*)gemm2,
                            hipFuncAttributeMaxDynamicSharedMemorySize, 131072);

  prep<<<513, 1024, 0, stream>>>(rewards, G, W1, W2, BT1, BT2);
  for (int c = 0; c < 4; ++c) {
    const size_t eoff = (size_t)c * 16777216;  // 16384 rows x 1024
    conv<<<512, 1024, 0, stream>>>(obs + eoff, obsb + eoff);
    gemm1<<<256, 512, 131072, stream>>>(obsb, BT1, b1, h1, c * 64);
    gemm2<<<256, 512, 131072, stream>>>(h1, BT2, b2, W3, V4, c * 64);
  }
  final_kernel<<<256, 256, 0, stream>>>(G, V4, b3, out);
}

// Round 18
// 339.188 us; speedup vs baseline: 1.1285x; 1.1285x over previous
//
#include <hip/hip_runtime.h>

typedef __bf16 bf16x8 __attribute__((ext_vector_type(8)));
typedef __bf16 bf16x4 __attribute__((ext_vector_type(4)));
typedef float  f32x4  __attribute__((ext_vector_type(4)));

#define GAMMA 0.99f

__device__ __forceinline__ void gload_lds16(const void* g, void* l) {
  __builtin_amdgcn_global_load_lds(
      (const __attribute__((address_space(1))) void*)g,
      (__attribute__((address_space(3))) void*)l, 16, 0, 0);
}

#define VMCNT(n) asm volatile("s_waitcnt vmcnt(" #n ")" ::: "memory")
#define BAR() __builtin_amdgcn_s_barrier()
#define MFMA(d, a, b) d = __builtin_amdgcn_mfma_f32_16x16x32_bf16(a, b, d, 0, 0, 0)

// ------------------------------------------------- mega: scan + converts ----
// block 0            : discounted-return scan (1024 threads)
// blocks 1..2048     : obs fp32 -> bf16 convert; NT LOADS only (R15: NT
//                      stores cost gemm1 +22us > mega's -13us saving)
// blocks 2049..2560  : W1/W2 transpose+cvt -> BT1/BT2 (4 subtiles per block)
__global__ __launch_bounds__(1024) void mega_prep(
    const float* __restrict__ rw, float* __restrict__ G,
    const float* __restrict__ obs, __bf16* __restrict__ obsb,
    const float* __restrict__ W1, const float* __restrict__ W2,
    __bf16* __restrict__ BT1, __bf16* __restrict__ BT2) {
  __shared__ float smem[4224];
  const int blk = blockIdx.x;
  const int t = threadIdx.x;
  if (blk == 0) {
    // ---- scan ----
    float* sv = smem;
    const float4* rp = (const float4*)(rw + t * 64);
    float4 lv[16];
#pragma unroll
    for (int i = 0; i < 16; ++i) lv[i] = rp[i];
    float loc[64];
#pragma unroll
    for (int i = 0; i < 16; ++i) {
      loc[4 * i + 0] = lv[i].x; loc[4 * i + 1] = lv[i].y;
      loc[4 * i + 2] = lv[i].z; loc[4 * i + 3] = lv[i].w;
    }
    float g = 0.f;
#pragma unroll
    for (int j = 63; j >= 0; --j) { g = loc[j] + GAMMA * g; loc[j] = g; }
    sv[t] = g;
    float W = GAMMA;
#pragma unroll
    for (int i = 0; i < 6; ++i) W *= W;  // gamma^64
    float v = g;
    for (int s = 1; s < 1024; s <<= 1) {
      __syncthreads();
      float o = (t + s < 1024) ? sv[t + s] : 0.f;
      __syncthreads();
      v += W * o;
      sv[t] = v;
      W *= W;
    }
    __syncthreads();
    const float nxt = (t < 1023) ? sv[t + 1] : 0.f;
    float pw = GAMMA;
#pragma unroll
    for (int j = 63; j >= 0; --j) {
      G[t * 64 + j] = loc[j] + pw * nxt;
      pw *= GAMMA;
    }
  } else if (blk <= 2048) {
    // ---- obs convert: 32768 elems per block, NT loads, regular stores ----
    const size_t base = (size_t)(blk - 1) * 32768 + (size_t)t * 8;
#pragma unroll
    for (int it = 0; it < 4; ++it) {
      const size_t e = base + (size_t)it * 8192;
      const f32x4* p = (const f32x4*)(obs + e);
      f32x4 u0 = __builtin_nontemporal_load(p);
      f32x4 u1 = __builtin_nontemporal_load(p + 1);
      bf16x8 o = {(__bf16)u0[0], (__bf16)u0[1], (__bf16)u0[2], (__bf16)u0[3],
                  (__bf16)u1[0], (__bf16)u1[1], (__bf16)u1[2], (__bf16)u1[3]};
      *(bf16x8*)(obsb + e) = o;
    }
  } else {
    // ---- W transpose+cvt: 4 subtiles of 32x32 per block ----
    const int sub = t >> 8, tt = t & 255;
    const int wi = (blk - 2049) * 4 + sub;  // 0..2047
    const float* W = (wi >= 1024) ? W2 : W1;
    __bf16* O = (wi >= 1024) ? BT2 : BT1;
    const int tile = wi & 1023;
    const int ti = tile >> 5, tj = tile & 31;
    float* s = smem + sub * 1056;  // [32][33]
    const int rr = tt >> 3, c4 = (tt & 7) * 4;
    float4 v = *(const float4*)(W + (size_t)(ti * 32 + rr) * 1024 + tj * 32 + c4);
    s[rr * 33 + c4 + 0] = v.x; s[rr * 33 + c4 + 1] = v.y;
    s[rr * 33 + c4 + 2] = v.z; s[rr * 33 + c4 + 3] = v.w;
    __syncthreads();
    bf16x4 o = {(__bf16)s[(c4 + 0) * 33 + rr], (__bf16)s[(c4 + 1) * 33 + rr],
                (__bf16)s[(c4 + 2) * 33 + rr], (__bf16)s[(c4 + 3) * 33 + rr]};
    *(bf16x4*)(O + (size_t)(tj * 32 + rr) * 1024 + ti * 32 + c4) = o;
  }
}

// ---------------------------------------------------------------------------
// GEMM core (best measured, R11): BM=BN=256, BK=32, 512 thr = 8 waves (2x4).
// FOUR LDS buffers of 32 KB {A 16K | B 16K}, bf16, 64-B rows, chunk c at slot
// c^((r>>1)&3). 3-tile-deep pipeline, counted vmcnt (never 0 in main loop):
// entering iter kt: 12 outstanding; issue tile kt+3 (4) -> 16; VMCNT(12)
// retires exactly tile kt. Peel VMCNT(8)/(4)/(0).
// SWAPPED MFMA: D = B_frag x A_frag -> acc regs = 4 consecutive n-cols of one
// m-row -> direct vector stores, no LDS epilogue round-trip.
// launch_bounds (512,2): (512,4) caps VGPR at 64 -> acc spills (R5 lesson).
// ---------------------------------------------------------------------------
#define GEMM_KLOOP(APTR, BPTR)                                                 \
  extern __shared__ char lds[];                                                \
  const int t = threadIdx.x, lane = t & 63, w = t >> 6;                        \
  const int wsr = w >> 2, wsc = w & 3, g = lane >> 4, l15 = lane & 15;         \
  const int bid = blockIdx.x;                                                  \
  const int mb = (bid & 7) * 32 + ((bid >> 3) >> 2);                           \
  const int nb = (bid >> 3) & 3;                                               \
  const size_t stg_off =                                                       \
      (size_t)(t >> 2) * 2048 + (size_t)(((t & 3) ^ ((t >> 3) & 3)) * 16);     \
  const char* Ag = (const char*)(APTR) + (size_t)mb * 524288 + stg_off;        \
  const char* Bg = (const char*)(BPTR) + (size_t)nb * 524288 + stg_off;        \
  const int csw = (g ^ ((l15 >> 1) & 3)) << 4;                                 \
  const int arb = (wsr * 64 + l15) * 64 + csw;                                 \
  const int brb = (wsc * 32 + l15) * 64 + csw + 16384;                         \
  f32x4 acc[2][4][2][2];                                                       \
  const f32x4 zero = {0.f, 0.f, 0.f, 0.f};                                     \
  _Pragma("unroll") for (int a_ = 0; a_ < 2; ++a_)                             \
  _Pragma("unroll") for (int b_ = 0; b_ < 4; ++b_)                             \
  _Pragma("unroll") for (int c_ = 0; c_ < 2; ++c_)                             \
  _Pragma("unroll") for (int d_ = 0; d_ < 2; ++d_)                             \
    acc[a_][b_][c_][d_] = zero;                                                \
  auto STA = [&](int buf, int kt) {                                            \
    const char* s = Ag + kt * 64;                                              \
    char* d = lds + buf * 32768 + t * 16;                                      \
    gload_lds16(s, d);                                                         \
    gload_lds16(s + 262144, d + 8192);                                         \
  };                                                                           \
  auto STB = [&](int buf, int kt) {                                            \
    const char* s = Bg + kt * 64;                                              \
    char* d = lds + buf * 32768 + 16384 + t * 16;                              \
    gload_lds16(s, d);                                                         \
    gload_lds16(s + 262144, d + 8192);                                         \
  };                                                                           \
  auto COMPUTE = [&](int bc) {                                                 \
    const char* ab = lds + bc * 32768;                                         \
    bf16x8 bfr[2][2], afr[4];                                                  \
    _Pragma("unroll") for (int nh = 0; nh < 2; ++nh)                           \
    _Pragma("unroll") for (int j = 0; j < 2; ++j)                              \
      bfr[nh][j] = *(const bf16x8*)(ab + brb + (nh * 128 + j * 16) * 64);      \
    _Pragma("unroll") for (int i = 0; i < 4; ++i)                              \
      afr[i] = *(const bf16x8*)(ab + arb + (i * 16) * 64);                     \
    __builtin_amdgcn_s_setprio(1);                                             \
    _Pragma("unroll") for (int i = 0; i < 4; ++i)                              \
    _Pragma("unroll") for (int nh = 0; nh < 2; ++nh)                           \
    _Pragma("unroll") for (int j = 0; j < 2; ++j)                              \
      MFMA(acc[0][i][nh][j], bfr[nh][j], afr[i]);                              \
    __builtin_amdgcn_s_setprio(0);                                             \
    _Pragma("unroll") for (int i = 0; i < 4; ++i)                              \
      afr[i] = *(const bf16x8*)(ab + arb + ((128 + i * 16) * 64));             \
    __builtin_amdgcn_s_setprio(1);                                             \
    _Pragma("unroll") for (int i = 0; i < 4; ++i)                              \
    _Pragma("unroll") for (int nh = 0; nh < 2; ++nh)                           \
    _Pragma("unroll") for (int j = 0; j < 2; ++j)                              \
      MFMA(acc[1][i][nh][j], bfr[nh][j], afr[i]);                              \
    __builtin_amdgcn_s_setprio(0);                                             \
  };                                                                           \
  STA(0, 0); STB(0, 0);                                                        \
  STA(1, 1); STB(1, 1);                                                        \
  STA(2, 2); STB(2, 2);                                                        \
  int bc = 0;                                                                  \
  for (int kt = 0; kt < 29; ++kt) {                                            \
    int bs = bc + 3; if (bs >= 4) bs -= 4;                                     \
    STA(bs, kt + 3);                                                           \
    STB(bs, kt + 3);                                                           \
    VMCNT(12);                                                                 \
    BAR();                                                                     \
    COMPUTE(bc);                                                               \
    BAR();                                                                     \
    bc = (bc + 1) & 3;                                                         \
  }                                                                            \
  VMCNT(8);                                                                    \
  BAR();                                                                       \
  COMPUTE(bc);                                                                 \
  BAR();                                                                       \
  bc = (bc + 1) & 3;                                                           \
  VMCNT(4);                                                                    \
  BAR();                                                                       \
  COMPUTE(bc);                                                                 \
  BAR();                                                                       \
  bc = (bc + 1) & 3;                                                           \
  VMCNT(0);                                                                    \
  BAR();                                                                       \
  COMPUTE(bc);

// ---------------------------------------------------------------- GEMM1 ----
// h1 = relu(obs_bf16 @ W1 + b1); direct bf16x4 stores
__global__ __launch_bounds__(512, 2) void gemm1(
    const __bf16* __restrict__ obsb, const __bf16* __restrict__ BT1,
    const float* __restrict__ b1, __bf16* __restrict__ h1) {
  GEMM_KLOOP(obsb, BT1)
  f32x4 b1q[2][2];
#pragma unroll
  for (int nh = 0; nh < 2; ++nh)
#pragma unroll
    for (int j = 0; j < 2; ++j)
      b1q[nh][j] =
          *(const f32x4*)(b1 + nb * 256 + nh * 128 + wsc * 32 + j * 16 + g * 4);
#pragma unroll
  for (int mh = 0; mh < 2; ++mh)
#pragma unroll
    for (int i = 0; i < 4; ++i) {
      const size_t mrow = (size_t)(mb * 256 + mh * 128 + wsr * 64 + i * 16 + l15);
#pragma unroll
      for (int nh = 0; nh < 2; ++nh)
#pragma unroll
        for (int j = 0; j < 2; ++j) {
          f32x4 v = acc[mh][i][nh][j];
          v.x += b1q[nh][j].x; v.y += b1q[nh][j].y;
          v.z += b1q[nh][j].z; v.w += b1q[nh][j].w;
          v.x = v.x > 0.f ? v.x : 0.f;
          v.y = v.y > 0.f ? v.y : 0.f;
          v.z = v.z > 0.f ? v.z : 0.f;
          v.w = v.w > 0.f ? v.w : 0.f;
          bf16x4 o = {(__bf16)v.x, (__bf16)v.y, (__bf16)v.z, (__bf16)v.w};
          *(bf16x4*)(h1 + mrow * 1024 + nb * 256 + nh * 128 + wsc * 32 +
                     j * 16 + g * 4) = o;
        }
    }
}

// ---------------------------------------------------------------- GEMM2 ----
// h2 = relu(h1 @ W2 + b2); fused V4[nb][m] = sum_c h2[m][c]*W3[c]
__global__ __launch_bounds__(512, 2) void gemm2(
    const __bf16* __restrict__ h1, const __bf16* __restrict__ BT2,
    const float* __restrict__ b2, const float* __restrict__ W3,
    float* __restrict__ V4) {
  GEMM_KLOOP(h1, BT2)
  f32x4 b2q[2][2], w3q[2][2];
#pragma unroll
  for (int nh = 0; nh < 2; ++nh)
#pragma unroll
    for (int j = 0; j < 2; ++j) {
      const int C = nb * 256 + nh * 128 + wsc * 32 + j * 16 + g * 4;
      b2q[nh][j] = *(const f32x4*)(b2 + C);
      w3q[nh][j] = *(const f32x4*)(W3 + C);
    }
  float p[2][4];
#pragma unroll
  for (int mh = 0; mh < 2; ++mh)
#pragma unroll
    for (int i = 0; i < 4; ++i) {
      float s = 0.f;
#pragma unroll
      for (int nh = 0; nh < 2; ++nh)
#pragma unroll
        for (int j = 0; j < 2; ++j) {
          f32x4 v = acc[mh][i][nh][j];
          v.x += b2q[nh][j].x; v.y += b2q[nh][j].y;
          v.z += b2q[nh][j].z; v.w += b2q[nh][j].w;
          v.x = v.x > 0.f ? v.x : 0.f;
          v.y = v.y > 0.f ? v.y : 0.f;
          v.z = v.z > 0.f ? v.z : 0.f;
          v.w = v.w > 0.f ? v.w : 0.f;
          s += v.x * w3q[nh][j].x + v.y * w3q[nh][j].y +
               v.z * w3q[nh][j].z + v.w * w3q[nh][j].w;
        }
      p[mh][i] = s;
    }
#pragma unroll
  for (int mh = 0; mh < 2; ++mh)
#pragma unroll
    for (int i = 0; i < 4; ++i) {
      p[mh][i] += __shfl_xor(p[mh][i], 16, 64);
      p[mh][i] += __shfl_xor(p[mh][i], 32, 64);
    }
  float* vp = (float*)lds;  // buf0; final COMPUTE reads buf3 -> no overlap
  if (g == 0) {
#pragma unroll
    for (int mh = 0; mh < 2; ++mh)
#pragma unroll
      for (int i = 0; i < 4; ++i)
        vp[wsc * 256 + mh * 128 + wsr * 64 + i * 16 + l15] = p[mh][i];
  }
  __syncthreads();
  if (t < 256) {
    float s = vp[t] + vp[256 + t] + vp[512 + t] + vp[768 + t];
    V4[(size_t)nb * 65536 + mb * 256 + t] = s;
  }
}

// ---------------------------------------------------------------- final ----
__global__ __launch_bounds__(256) void final_kernel(const float* __restrict__ G,
                                                    const float* __restrict__ V4,
                                                    const float* __restrict__ b3,
                                                    float* __restrict__ out) {
  int i = blockIdx.x * 256 + threadIdx.x;
  out[i] = G[i] - (V4[i] + V4[65536 + i] + V4[131072 + i] + V4[196608 + i] + b3[0]);
}

extern "C" void kernel_launch(void* const* d_in, const int* in_sizes, int n_in,
                              void* d_out, int out_size, void* d_ws, size_t ws_size,
                              hipStream_t stream) {
  const float* rewards = (const float*)d_in[0];
  const float* obs = (const float*)d_in[1];
  const float* W1 = (const float*)d_in[2];
  const float* b1 = (const float*)d_in[3];
  const float* W2 = (const float*)d_in[4];
  const float* b2 = (const float*)d_in[5];
  const float* W3 = (const float*)d_in[6];
  const float* b3 = (const float*)d_in[7];
  float* out = (float*)d_out;

  char* ws = (char*)d_ws;
  __bf16* BT1 = (__bf16*)(ws);                 // 2 MiB
  __bf16* BT2 = (__bf16*)(ws + (2u << 20));    // 2 MiB
  float* V4 = (float*)(ws + (4u << 20));       // 1 MiB
  float* G = (float*)(ws + (5u << 20));        // 256 KiB
  __bf16* obsb = (__bf16*)(ws + (8u << 20));   // 128 MiB
  __bf16* h1 = (__bf16*)(ws + (136u << 20));   // 128 MiB

  (void)hipFuncSetAttribute((const void*)gemm1,
                            hipFuncAttributeMaxDynamicSharedMemorySize, 131072);
  (void)hipFuncSetAttribute((const void*)gemm2,
                            hipFuncAttributeMaxDynamicSharedMemorySize, 131072);

  mega_prep<<<2561, 1024, 0, stream>>>(rewards, G, obs, obsb, W1, W2, BT1, BT2);
  gemm1<<<1024, 512, 131072, stream>>>(obsb, BT1, b1, h1);
  gemm2<<<1024, 512, 131072, stream>>>(h1, BT2, b2, W3, V4);
  final_kernel<<<256, 256, 0, stream>>>(G, V4, b3, out);
}